// Round 1
// baseline (413.789 us; speedup 1.0000x reference)
//
#include <hip/hip_runtime.h>

typedef __attribute__((ext_vector_type(8))) short bf16x8;
typedef __attribute__((ext_vector_type(4))) short bf16x4;
typedef __attribute__((ext_vector_type(4))) float f32x4;

#define MFMA16(a, b, c) __builtin_amdgcn_mfma_f32_16x16x32_bf16((a), (b), (c), 0, 0, 0)

__device__ __forceinline__ short f2bf(float f) {
  union { float f; unsigned u; } v; v.f = f;
  unsigned r = v.u + 0x7FFFu + ((v.u >> 16) & 1u);   // RNE
  return (short)(r >> 16);
}

__device__ __forceinline__ void async16(const void* g, void* l) {
  __builtin_amdgcn_global_load_lds(
      (const __attribute__((address_space(1))) unsigned*)g,
      (__attribute__((address_space(3))) unsigned*)l, 16, 0, 0);
}

// ---------------- Projection: Q = (x@Wq^T + bq)/16, K = x@Wk^T + bk (bf16 row-major),
// ---------------- VT = (x@Wv^T + bv)^T  (bf16, [B][D][S])
__global__ __launch_bounds__(256, 1) void proj_kernel(
    const float* __restrict__ x,
    const float* __restrict__ Wq, const float* __restrict__ bq,
    const float* __restrict__ Wk, const float* __restrict__ bk,
    const float* __restrict__ Wv, const float* __restrict__ bv,
    short* __restrict__ Qb, short* __restrict__ Kb, short* __restrict__ VTb)
{
  __shared__ __attribute__((aligned(16))) char xs[32768]; // x tile [64][256] bf16, XOR-swizzled
  const int tid = threadIdx.x;
  const int lane = tid & 63;
  const int w = tid >> 6;
  const int l15 = lane & 15, lg = lane >> 4;
  const int m0 = blockIdx.x * 64;
  const int z = blockIdx.y;
  const float* W    = (z == 0) ? Wq : (z == 1) ? Wk : Wv;
  const float* bias = (z == 0) ? bq : (z == 1) ? bk : bv;

  // stage x[m0..+64][0..256] fp32 -> bf16 LDS, swizzle 16B units: u' = u ^ (row&7)
  #pragma unroll
  for (int c = 0; c < 8; ++c) {
    int v = c * 256 + tid;          // 16B-unit index, 2048 total
    int row = v >> 5, u = v & 31;
    const float* g = x + (size_t)(m0 + row) * 256 + u * 8;
    float4 a = *(const float4*)g;
    float4 b = *(const float4*)(g + 4);
    bf16x8 h;
    h[0]=f2bf(a.x); h[1]=f2bf(a.y); h[2]=f2bf(a.z); h[3]=f2bf(a.w);
    h[4]=f2bf(b.x); h[5]=f2bf(b.y); h[6]=f2bf(b.z); h[7]=f2bf(b.w);
    *(bf16x8*)(xs + row * 512 + ((u ^ (row & 7)) * 16)) = h;
  }
  __syncthreads();

  if (z < 2) {
    // wave w: rows m0 + w*16 .. +16, all 256 e-cols
    bf16x8 xa[8];
    #pragma unroll
    for (int ks = 0; ks < 8; ++ks) {
      int row = w * 16 + l15;
      xa[ks] = *(const bf16x8*)(xs + row * 512 + (((ks * 4 + lg) ^ (row & 7)) * 16));
    }
    short* Ob = (z == 0) ? Qb : Kb;
    const float scl = (z == 0) ? 0.0625f : 1.0f;
    #pragma unroll 4
    for (int fc = 0; fc < 16; ++fc) {
      const float* wrow = W + (size_t)(fc * 16 + l15) * 256;
      f32x4 acc = {0.f, 0.f, 0.f, 0.f};
      #pragma unroll
      for (int ks = 0; ks < 8; ++ks) {
        const float* p = wrow + ks * 32 + lg * 8;
        float4 a = *(const float4*)p;
        float4 b = *(const float4*)(p + 4);
        bf16x8 wf;
        wf[0]=f2bf(a.x); wf[1]=f2bf(a.y); wf[2]=f2bf(a.z); wf[3]=f2bf(a.w);
        wf[4]=f2bf(b.x); wf[5]=f2bf(b.y); wf[6]=f2bf(b.z); wf[7]=f2bf(b.w);
        acc = MFMA16(xa[ks], wf, acc);
      }
      float bb = bias[fc * 16 + l15];
      short* orow0 = Ob + (size_t)(m0 + w * 16) * 256 + fc * 16 + l15;
      #pragma unroll
      for (int r = 0; r < 4; ++r) {
        float vv = (acc[r] + bb) * scl;
        orow0[(size_t)(lg * 4 + r) * 256] = f2bf(vv);
      }
    }
  } else {
    // VT: wave w owns e in [w*64, w*64+64)
    const int batch = m0 >> 12;
    const int s0 = (m0 & 4095);
    #pragma unroll
    for (int fc = 0; fc < 4; ++fc) {
      bf16x8 xb[8];
      #pragma unroll
      for (int ks = 0; ks < 8; ++ks) {
        int row = fc * 16 + l15;
        xb[ks] = *(const bf16x8*)(xs + row * 512 + (((ks * 4 + lg) ^ (row & 7)) * 16));
      }
      #pragma unroll
      for (int fr = 0; fr < 4; ++fr) {
        const float* wrow = W + (size_t)(w * 64 + fr * 16 + l15) * 256;
        f32x4 acc = {0.f, 0.f, 0.f, 0.f};
        #pragma unroll
        for (int ks = 0; ks < 8; ++ks) {
          const float* p = wrow + ks * 32 + lg * 8;
          float4 a = *(const float4*)p;
          float4 b = *(const float4*)(p + 4);
          bf16x8 wf;
          wf[0]=f2bf(a.x); wf[1]=f2bf(a.y); wf[2]=f2bf(a.z); wf[3]=f2bf(a.w);
          wf[4]=f2bf(b.x); wf[5]=f2bf(b.y); wf[6]=f2bf(b.z); wf[7]=f2bf(b.w);
          acc = MFMA16(wf, xb[ks], acc);
        }
        int scol = s0 + fc * 16 + l15;
        #pragma unroll
        for (int r = 0; r < 4; ++r) {
          int e = w * 64 + fr * 16 + lg * 4 + r;
          float vv = acc[r] + bias[e];
          VTb[(size_t)(batch * 256 + e) * 4096 + scol] = f2bf(vv);
        }
      }
    }
  }
}

// ---------------- Flash attention: BM=64 q-rows/block (16/wave), BN=64 kv/tile,
// ---------------- swapped QK^T (S^T accum), double-buffered K/VT staging.
__global__ __launch_bounds__(256, 1) void attn_kernel(
    const short* __restrict__ Qb, const short* __restrict__ Kb,
    const short* __restrict__ VTb, float* __restrict__ out)
{
  // LDS: [buf0: K 32KB | VT 32KB][buf1: K 32KB | VT 32KB][P: 4 waves x 2KB]
  __shared__ __attribute__((aligned(16))) char smem[139264];
  const int tid = threadIdx.x;
  const int lane = tid & 63;
  const int w = tid >> 6;
  const int l15 = lane & 15, lg = lane >> 4;

  // XCD-bijective swizzle: xcd = b%8 -> batch = xcd>>1 (each batch's K/VT pinned to 2 XCDs)
  const int b = blockIdx.x;
  const int xcd = b & 7;
  const int batch = xcd >> 1;
  const int qt = ((b >> 3) << 1) | (xcd & 1);     // 0..63
  const int q0 = qt * 64;

  const char* Kbase  = (const char*)(Kb  + (size_t)batch * 4096 * 256);
  const char* VTbase = (const char*)(VTb + (size_t)batch * 256 * 4096);

  // Q fragments (B-operand pattern), scale already folded in
  bf16x8 qf[8];
  {
    const short* qrow = Qb + (size_t)(batch * 4096 + q0 + w * 16 + l15) * 256;
    #pragma unroll
    for (int db = 0; db < 8; ++db)
      qf[db] = *(const bf16x8*)(qrow + db * 32 + lg * 8);
  }

  f32x4 o[16];
  #pragma unroll
  for (int i = 0; i < 16; ++i) o[i] = (f32x4){0.f, 0.f, 0.f, 0.f};
  float m_run = -1e30f, l_run = 0.f;

  char* pl = smem + 131072 + w * 2048;   // per-wave P tile [16 q][64 kv] bf16, swizzled 8B units

  auto stage = [&](int buf, int kv0) {
    const char* kg = Kbase + (size_t)kv0 * 512;
    char* kl = smem + buf * 65536;
    #pragma unroll
    for (int c = 0; c < 8; ++c) {
      int v = c * 256 + tid;            // 0..2047
      int row = v >> 5, s = v & 31;
      int u = s ^ (row & 7);            // pre-swizzled global source (linear LDS dest)
      async16(kg + row * 512 + u * 16, kl + (c * 256 + w * 64) * 16);
    }
    const char* vg = VTbase + (size_t)kv0 * 2;
    char* vl = smem + buf * 65536 + 32768;
    #pragma unroll
    for (int c = 0; c < 8; ++c) {
      int v = c * 256 + tid;            // 0..2047 ; row = d (0..255), 8 units/row
      int row = v >> 3, s = v & 7;
      int u = s ^ (row & 7);
      async16(vg + (size_t)row * 8192 + u * 16, vl + (c * 256 + w * 64) * 16);
    }
  };

  stage(0, 0);
  __syncthreads();

  for (int t = 0; t < 64; ++t) {
    const int cur = t & 1;
    if (t < 63) stage(cur ^ 1, (t + 1) * 64);   // async prefetch, drained at end barrier

    const char* kl = smem + cur * 65536;
    const char* vl = kl + 32768;

    // ---- QK^T (swapped): st[f](lane,r) = S[q=l15][kv = f*16 + lg*4 + r]
    f32x4 st[4];
    #pragma unroll
    for (int f = 0; f < 4; ++f) st[f] = (f32x4){0.f, 0.f, 0.f, 0.f};
    #pragma unroll
    for (int db = 0; db < 8; ++db) {
      #pragma unroll
      for (int f = 0; f < 4; ++f) {
        int row = f * 16 + l15;
        bf16x8 kf = *(const bf16x8*)(kl + row * 512 + (((db * 4 + lg) ^ (row & 7)) * 16));
        st[f] = MFMA16(kf, qf[db], st[f]);
      }
    }

    // ---- online softmax over this tile (q = l15; reduce 16 in-lane + shfl 16/32)
    float mx = -1e30f;
    #pragma unroll
    for (int f = 0; f < 4; ++f) {
      mx = fmaxf(mx, fmaxf(fmaxf(st[f][0], st[f][1]), fmaxf(st[f][2], st[f][3])));
    }
    mx = fmaxf(mx, __shfl_xor(mx, 16));
    mx = fmaxf(mx, __shfl_xor(mx, 32));
    float m_new = fmaxf(m_run, mx);
    float alpha = __expf(m_run - m_new);
    float lsum = 0.f;
    #pragma unroll
    for (int f = 0; f < 4; ++f) {
      bf16x4 pv;
      #pragma unroll
      for (int r = 0; r < 4; ++r) {
        float pe = __expf(st[f][r] - m_new);
        lsum += pe;
        pv[r] = f2bf(pe);
      }
      int u8 = (f * 4 + lg) ^ ((l15 & 7) << 1);
      *(bf16x4*)(pl + l15 * 128 + u8 * 8) = pv;
    }
    lsum += __shfl_xor(lsum, 16);
    lsum += __shfl_xor(lsum, 32);
    l_run = l_run * alpha + lsum;
    m_run = m_new;

    // ---- rescale O: O rows are q_local = lg*4 + r; alpha lives at lane q_local
    float ar0 = __shfl(alpha, lg * 4 + 0);
    float ar1 = __shfl(alpha, lg * 4 + 1);
    float ar2 = __shfl(alpha, lg * 4 + 2);
    float ar3 = __shfl(alpha, lg * 4 + 3);
    #pragma unroll
    for (int df = 0; df < 16; ++df) {
      o[df][0] *= ar0; o[df][1] *= ar1; o[df][2] *= ar2; o[df][3] *= ar3;
    }

    // ---- PV: O[q][d] += P[q][kv] @ V[kv][d]  (B-operand = VT rows)
    #pragma unroll
    for (int ks = 0; ks < 2; ++ks) {
      int u8p = (ks * 8 + lg * 2) ^ ((l15 & 7) << 1);
      bf16x8 pa = *(const bf16x8*)(pl + l15 * 128 + u8p * 8);
      #pragma unroll
      for (int df = 0; df < 16; ++df) {
        int row = df * 16 + l15;
        bf16x8 vb = *(const bf16x8*)(vl + row * 128 + (((ks * 4 + lg) ^ (row & 7)) * 16));
        o[df] = MFMA16(pa, vb, o[df]);
      }
    }

    __syncthreads();   // drains prefetch vmcnt + protects buffer swap
  }

  // ---- epilogue: divide by softmax denom, store fp32
  float lr0 = 1.f / __shfl(l_run, lg * 4 + 0);
  float lr1 = 1.f / __shfl(l_run, lg * 4 + 1);
  float lr2 = 1.f / __shfl(l_run, lg * 4 + 2);
  float lr3 = 1.f / __shfl(l_run, lg * 4 + 3);
  float* ob = out + (size_t)(batch * 4096 + q0 + w * 16) * 256;
  #pragma unroll
  for (int df = 0; df < 16; ++df) {
    int col = df * 16 + l15;
    ob[(size_t)(lg * 4 + 0) * 256 + col] = o[df][0] * lr0;
    ob[(size_t)(lg * 4 + 1) * 256 + col] = o[df][1] * lr1;
    ob[(size_t)(lg * 4 + 2) * 256 + col] = o[df][2] * lr2;
    ob[(size_t)(lg * 4 + 3) * 256 + col] = o[df][3] * lr3;
  }
}

extern "C" void kernel_launch(void* const* d_in, const int* in_sizes, int n_in,
                              void* d_out, int out_size, void* d_ws, size_t ws_size,
                              hipStream_t stream) {
  const float* x  = (const float*)d_in[0];
  const float* Wq = (const float*)d_in[1];
  const float* bq = (const float*)d_in[2];
  const float* Wk = (const float*)d_in[3];
  const float* bk = (const float*)d_in[4];
  const float* Wv = (const float*)d_in[5];
  const float* bv = (const float*)d_in[6];
  float* out = (float*)d_out;

  short* Qb  = (short*)d_ws;                    // [16384][256] bf16 (scale folded)
  short* Kb  = Qb + (size_t)16384 * 256;        // [16384][256] bf16
  short* VTb = Kb + (size_t)16384 * 256;        // [4][256][4096] bf16

  proj_kernel<<<dim3(256, 3, 1), dim3(256, 1, 1), 0, stream>>>(
      x, Wq, bq, Wk, bk, Wv, bv, Qb, Kb, VTb);
  attn_kernel<<<dim3(256, 1, 1), dim3(256, 1, 1), 0, stream>>>(
      Qb, Kb, VTb, out);
}

// Round 2
// 191.001 us; speedup vs baseline: 2.1664x; 2.1664x over previous
//
#include <hip/hip_runtime.h>

typedef __attribute__((ext_vector_type(8))) short bf16x8;
typedef __attribute__((ext_vector_type(4))) short bf16x4;
typedef __attribute__((ext_vector_type(4))) float f32x4;
typedef __attribute__((ext_vector_type(16))) float f32x16;

#define MFMA16(a,b,c) __builtin_amdgcn_mfma_f32_16x16x32_bf16((a),(b),(c),0,0,0)
#define MFMA32(a,b,c) __builtin_amdgcn_mfma_f32_32x32x16_bf16((a),(b),(c),0,0,0)

__device__ __forceinline__ short f2bf(float f) {
  union { float f; unsigned u; } v; v.f = f;
  unsigned r = v.u + 0x7FFFu + ((v.u >> 16) & 1u);   // RNE
  return (short)(r >> 16);
}

__device__ __forceinline__ void async16(const void* g, void* l) {
  __builtin_amdgcn_global_load_lds(
      (const __attribute__((address_space(1))) unsigned*)g,
      (__attribute__((address_space(3))) unsigned*)l, 16, 0, 0);
}

// ------------- convert Wq/Wk/Wv fp32 -> bf16 [3][256][256] -------------
__global__ void cvt_w_kernel(const float* __restrict__ Wq, const float* __restrict__ Wk,
                             const float* __restrict__ Wv, short* __restrict__ Wb) {
  int v = blockIdx.x * 256 + threadIdx.x;        // 24576 units of 8 elems
  int z = v >> 13, r = v & 8191;
  const float* src = ((z == 0) ? Wq : (z == 1) ? Wk : Wv) + r * 8;
  float4 a = *(const float4*)src;
  float4 b = *(const float4*)(src + 4);
  bf16x8 h;
  h[0]=f2bf(a.x); h[1]=f2bf(a.y); h[2]=f2bf(a.z); h[3]=f2bf(a.w);
  h[4]=f2bf(b.x); h[5]=f2bf(b.y); h[6]=f2bf(b.z); h[7]=f2bf(b.w);
  *(bf16x8*)(Wb + z * 65536 + r * 8) = h;
}

// ------------- proj: Q=(x Wq^T+bq)/16, K, VT (all bf16); W-frags in registers -------------
__global__ __launch_bounds__(256, 1) void proj_kernel(
    const float* __restrict__ x, const short* __restrict__ Wb,
    const float* __restrict__ bq, const float* __restrict__ bk, const float* __restrict__ bv,
    short* __restrict__ Qb, short* __restrict__ Kb, short* __restrict__ VTb)
{
  __shared__ __attribute__((aligned(16))) char xs[32768]; // x tile [64][256] bf16, swizzled
  const int tid = threadIdx.x;
  const int lane = tid & 63;
  const int w = tid >> 6;
  const int l15 = lane & 15, lg = lane >> 4;
  const int m0 = blockIdx.x * 64;
  const int batch = m0 >> 12;
  const int s0 = m0 & 4095;

  // stage x[m0..+64][256] fp32 -> bf16 LDS, 16B units swizzled u^(row&7)
  #pragma unroll
  for (int c = 0; c < 8; ++c) {
    int v = c * 256 + tid;
    int row = v >> 5, u = v & 31;
    const float* g = x + (size_t)(m0 + row) * 256 + u * 8;
    float4 a = *(const float4*)g;
    float4 b = *(const float4*)(g + 4);
    bf16x8 h;
    h[0]=f2bf(a.x); h[1]=f2bf(a.y); h[2]=f2bf(a.z); h[3]=f2bf(a.w);
    h[4]=f2bf(b.x); h[5]=f2bf(b.y); h[6]=f2bf(b.z); h[7]=f2bf(b.w);
    *(bf16x8*)(xs + row * 512 + ((u ^ (row & 7)) * 16)) = h;
  }
  __syncthreads();

  // Q and K: wave w owns e-cols [w*64, +64)
  for (int z = 0; z < 2; ++z) {
    const short* Wz = Wb + z * 65536;
    const float* bias = z ? bk : bq;
    short* Ob = z ? Kb : Qb;
    const float scl = z ? 1.0f : 0.0625f;
    bf16x8 wf[4][8];
    #pragma unroll
    for (int fc = 0; fc < 4; ++fc)
      #pragma unroll
      for (int ks = 0; ks < 8; ++ks)
        wf[fc][ks] = *(const bf16x8*)(Wz + (size_t)(w*64 + fc*16 + l15) * 256 + ks*32 + lg*8);
    float bb[4];
    #pragma unroll
    for (int fc = 0; fc < 4; ++fc) bb[fc] = bias[w*64 + fc*16 + l15];
    #pragma unroll
    for (int ms = 0; ms < 4; ++ms) {
      bf16x8 xa[8];
      #pragma unroll
      for (int ks = 0; ks < 8; ++ks) {
        int row = ms * 16 + l15;
        xa[ks] = *(const bf16x8*)(xs + row * 512 + (((ks*4 + lg) ^ (row & 7)) * 16));
      }
      f32x4 acc[4];
      #pragma unroll
      for (int fc = 0; fc < 4; ++fc) acc[fc] = (f32x4){0.f,0.f,0.f,0.f};
      #pragma unroll
      for (int ks = 0; ks < 8; ++ks)
        #pragma unroll
        for (int fc = 0; fc < 4; ++fc)
          acc[fc] = MFMA16(xa[ks], wf[fc][ks], acc[fc]);
      #pragma unroll
      for (int fc = 0; fc < 4; ++fc)
        #pragma unroll
        for (int r = 0; r < 4; ++r)
          Ob[(size_t)(m0 + ms*16 + lg*4 + r) * 256 + w*64 + fc*16 + l15] =
              f2bf((acc[fc][r] + bb[fc]) * scl);
    }
  }

  // V -> VT[batch][e][s]
  {
    const short* Wz = Wb + 2 * 65536;
    bf16x8 wf[4][8];
    #pragma unroll
    for (int fr = 0; fr < 4; ++fr)
      #pragma unroll
      for (int ks = 0; ks < 8; ++ks)
        wf[fr][ks] = *(const bf16x8*)(Wz + (size_t)(w*64 + fr*16 + l15) * 256 + ks*32 + lg*8);
    float bvr[4][4];
    #pragma unroll
    for (int fr = 0; fr < 4; ++fr)
      #pragma unroll
      for (int r = 0; r < 4; ++r) bvr[fr][r] = bv[w*64 + fr*16 + lg*4 + r];
    #pragma unroll
    for (int ms = 0; ms < 4; ++ms) {
      bf16x8 xa[8];
      #pragma unroll
      for (int ks = 0; ks < 8; ++ks) {
        int row = ms * 16 + l15;
        xa[ks] = *(const bf16x8*)(xs + row * 512 + (((ks*4 + lg) ^ (row & 7)) * 16));
      }
      f32x4 acc[4];
      #pragma unroll
      for (int fr = 0; fr < 4; ++fr) acc[fr] = (f32x4){0.f,0.f,0.f,0.f};
      #pragma unroll
      for (int ks = 0; ks < 8; ++ks)
        #pragma unroll
        for (int fr = 0; fr < 4; ++fr)
          acc[fr] = MFMA16(wf[fr][ks], xa[ks], acc[fr]);
      #pragma unroll
      for (int fr = 0; fr < 4; ++fr)
        #pragma unroll
        for (int r = 0; r < 4; ++r) {
          int e = w*64 + fr*16 + lg*4 + r;
          VTb[(size_t)(batch*256 + e) * 4096 + s0 + ms*16 + l15] = f2bf(acc[fr][r] + bvr[fr][r]);
        }
    }
  }
}

// ------------- flash attention: 8 waves, BM=128, BN=64, NS=2 kv-split, 32x32x16 MFMA -------------
// wave w: qs=w&3 (32 q rows), kh=w>>2 (kv half for QK; d half for PV). O computed transposed.
__global__ __launch_bounds__(512, 2) void attn_kernel(
    const short* __restrict__ Qb, const short* __restrict__ Kb,
    const short* __restrict__ VTb, float* __restrict__ Op, float* __restrict__ mlg)
{
  // [K0 32K][K1 32K][VT0 32K][VT1 32K][P 16K][ml 1K]
  __shared__ __attribute__((aligned(16))) char smem[148480];
  const int tid = threadIdx.x;
  const int lane = tid & 63;
  const int w = tid >> 6;
  const int l31 = lane & 31, hi = lane >> 5;
  const int qs = w & 3, kh = w >> 2, dh = kh;

  const int b = blockIdx.x;
  const int xcd = b & 7;                 // XCD-pin: one (batch,ns) per XCD
  const int batch = xcd >> 1, ns = xcd & 1;
  const int qt = b >> 3;
  const int q0 = qt * 128;
  const int kvbase = ns * 2048;

  const char* Kg = (const char*)(Kb  + (size_t)batch * 4096 * 256);
  const char* Vg = (const char*)(VTb + (size_t)batch * 256 * 4096);

  bf16x8 qf[16];
  {
    const short* qrow = Qb + (size_t)(batch*4096 + q0 + qs*32 + l31) * 256;
    #pragma unroll
    for (int ks = 0; ks < 16; ++ks) qf[ks] = *(const bf16x8*)(qrow + ks*16 + hi*8);
  }

  f32x16 o[4];
  #pragma unroll
  for (int i = 0; i < 4; ++i)
    #pragma unroll
    for (int r = 0; r < 16; ++r) o[i][r] = 0.f;
  float m_run = -1e30f, l_run = 0.f;

  float* ml = (float*)(smem + 147456);
  char* pl = smem + 131072 + qs * 4096;  // P[qs][32 q][64 kv] bf16, 8B units swizzled

  auto stage = [&](int buf, int kv0) {
    char* kl = smem + buf * 32768;
    #pragma unroll
    for (int c = 0; c < 4; ++c) {
      int v = c * 512 + tid;
      int row = v >> 5, s = v & 31;
      async16(Kg + (size_t)(kv0 + row) * 512 + ((s ^ (row & 7)) * 16),
              kl + (c * 512 + w * 64) * 16);
    }
    char* vl = smem + 65536 + buf * 32768;
    #pragma unroll
    for (int c = 0; c < 4; ++c) {
      int v = c * 512 + tid;
      int row = v >> 3, s = v & 7;
      async16(Vg + (size_t)row * 8192 + (size_t)kv0 * 2 + ((s ^ (row & 7)) * 16),
              vl + (c * 512 + w * 64) * 16);
    }
  };

  stage(0, kvbase);
  __syncthreads();

  for (int t = 0; t < 32; ++t) {
    const int cur = t & 1;
    if (t < 31) stage(cur ^ 1, kvbase + (t + 1) * 64);

    const char* kl = smem + cur * 32768;
    const char* vl = smem + 65536 + cur * 32768;

    // QK^T swapped: st = S^T[kv = kh*32 + row(r,hi)][q = l31]
    f32x16 st;
    #pragma unroll
    for (int r = 0; r < 16; ++r) st[r] = 0.f;
    #pragma unroll
    for (int ks = 0; ks < 16; ++ks) {
      int row = kh * 32 + l31;
      bf16x8 kf = *(const bf16x8*)(kl + row * 512 + (((ks*2 + hi) ^ (row & 7)) * 16));
      st = MFMA32(kf, qf[ks], st);
    }

    // online softmax (per q = l31)
    float mx = st[0];
    #pragma unroll
    for (int r = 1; r < 16; ++r) mx = fmaxf(mx, st[r]);
    mx = fmaxf(mx, __shfl_xor(mx, 32));
    if (!hi) ml[kh * 128 + qs * 32 + l31] = mx;
    asm volatile("s_waitcnt lgkmcnt(0)" ::: "memory");
    __builtin_amdgcn_s_barrier();                       // A: max exchange
    float mo = ml[(kh ^ 1) * 128 + qs * 32 + l31];
    float m_new = fmaxf(m_run, fmaxf(mx, mo));
    if (m_new > m_run) {                                // exact defer: alpha==1 -> skip
      float alpha = __expf(m_run - m_new);
      l_run *= alpha;
      #pragma unroll
      for (int df = 0; df < 4; ++df) o[df] = o[df] * alpha;
      m_run = m_new;
    }
    float ps[16];
    float lsum = 0.f;
    #pragma unroll
    for (int r = 0; r < 16; ++r) { ps[r] = __expf(st[r] - m_run); lsum += ps[r]; }
    l_run += lsum;
    #pragma unroll
    for (int g = 0; g < 4; ++g) {
      bf16x4 pv;
      #pragma unroll
      for (int j = 0; j < 4; ++j) pv[j] = f2bf(ps[4*g + j]);
      int qd = kh * 8 + 2 * g + hi;
      int u8 = qd ^ ((l31 & 7) << 1);
      *(bf16x4*)(pl + l31 * 128 + u8 * 8) = pv;
    }
    asm volatile("s_waitcnt lgkmcnt(0)" ::: "memory");
    __builtin_amdgcn_s_barrier();                       // B: P visible

    // PV as O^T: o = VT-frag (A, m=d) x P-frag (B, n=q)
    #pragma unroll
    for (int ks = 0; ks < 4; ++ks) {
      int u8 = (ks * 4 + hi * 2) ^ ((l31 & 7) << 1);
      bf16x8 pa = *(const bf16x8*)(pl + l31 * 128 + u8 * 8);
      #pragma unroll
      for (int df = 0; df < 4; ++df) {
        int row = dh * 128 + df * 32 + l31;
        bf16x8 vb = *(const bf16x8*)(vl + row * 128 + (((ks*2 + hi) ^ (row & 7)) * 16));
        o[df] = MFMA32(vb, pa, o[df]);
      }
    }
    __syncthreads();                                    // C: drains prefetch vmcnt
  }

  // epilogue: combine l across kv-halves, store unnormalized O^T -> Op, (m,l) -> mlg
  float lw = l_run + __shfl_xor(l_run, 32);
  if (!hi) ml[kh * 128 + qs * 32 + l31] = lw;
  asm volatile("s_waitcnt lgkmcnt(0)" ::: "memory");
  __builtin_amdgcn_s_barrier();
  float lt = ml[qs * 32 + l31] + ml[128 + qs * 32 + l31];
  const int qglob = batch * 4096 + q0 + qs * 32 + l31;
  float* op = Op + ((size_t)ns * 16384 + qglob) * 256;
  #pragma unroll
  for (int df = 0; df < 4; ++df)
    #pragma unroll
    for (int g = 0; g < 4; ++g) {
      float4 vv = {o[df][4*g], o[df][4*g+1], o[df][4*g+2], o[df][4*g+3]};
      *(float4*)(op + dh * 128 + df * 32 + 8 * g + 4 * hi) = vv;
    }
  if (kh == 0 && !hi) {
    mlg[((size_t)ns * 16384 + qglob) * 2]     = m_run;
    mlg[((size_t)ns * 16384 + qglob) * 2 + 1] = lt;
  }
}

// ------------- combine the two kv-split partials -------------
__global__ void combine_kernel(const float* __restrict__ Op, const float* __restrict__ mlg,
                               float* __restrict__ out) {
  int idx = blockIdx.x * 256 + threadIdx.x;     // 1,048,576 = 16384 rows x 64 float4
  int row = idx >> 6, c = idx & 63;
  float m0 = mlg[row * 2],           l0 = mlg[row * 2 + 1];
  float m1 = mlg[(16384 + row) * 2], l1 = mlg[(16384 + row) * 2 + 1];
  float ms = fmaxf(m0, m1);
  float a0 = __expf(m0 - ms), a1 = __expf(m1 - ms);
  float inv = 1.0f / (l0 * a0 + l1 * a1);
  a0 *= inv; a1 *= inv;
  float4 p0 = *(const float4*)(Op + (size_t)row * 256 + c * 4);
  float4 p1 = *(const float4*)(Op + (size_t)(16384 + row) * 256 + c * 4);
  float4 r;
  r.x = p0.x * a0 + p1.x * a1;
  r.y = p0.y * a0 + p1.y * a1;
  r.z = p0.z * a0 + p1.z * a1;
  r.w = p0.w * a0 + p1.w * a1;
  *(float4*)(out + (size_t)row * 256 + c * 4) = r;
}

extern "C" void kernel_launch(void* const* d_in, const int* in_sizes, int n_in,
                              void* d_out, int out_size, void* d_ws, size_t ws_size,
                              hipStream_t stream) {
  const float* x  = (const float*)d_in[0];
  const float* Wq = (const float*)d_in[1];
  const float* bq = (const float*)d_in[2];
  const float* Wk = (const float*)d_in[3];
  const float* bk = (const float*)d_in[4];
  const float* Wv = (const float*)d_in[5];
  const float* bv = (const float*)d_in[6];
  float* out = (float*)d_out;

  char* ws = (char*)d_ws;
  short* Qb  = (short*)(ws);                         // 8 MiB  [16384][256] bf16 (1/16 folded)
  short* Kb  = (short*)(ws + 8388608);               // 8 MiB  [16384][256] bf16
  short* VTb = (short*)(ws + 16777216);              // 8 MiB  [4][256][4096] bf16
  short* Wb  = (short*)(ws + 25165824);              // 384 KiB [3][256][256] bf16
  float* Op  = (float*)(ws + 25559040);              // 32 MiB [2][16384][256] f32
  float* mlg = (float*)(ws + 59113472);              // 256 KiB [2][16384][2] f32

  cvt_w_kernel<<<dim3(96), dim3(256), 0, stream>>>(Wq, Wk, Wv, Wb);
  proj_kernel<<<dim3(256), dim3(256), 0, stream>>>(x, Wb, bq, bk, bv, Qb, Kb, VTb);
  attn_kernel<<<dim3(256), dim3(512), 0, stream>>>(Qb, Kb, VTb, Op, mlg);
  combine_kernel<<<dim3(4096), dim3(256), 0, stream>>>(Op, mlg, out);
}